// Round 10
// baseline (7403.078 us; speedup 1.0000x reference)
//
#include <hip/hip_runtime.h>
#include <hip/hip_bf16.h>
#include <stdint.h>

typedef __bf16 bf16_t;
typedef __attribute__((ext_vector_type(8))) __bf16 bf16x8;
typedef __attribute__((ext_vector_type(4))) __bf16 bf16x4;
typedef __attribute__((ext_vector_type(4))) float f32x4;

constexpr int IN_F   = 4096;
constexpr int OUT_F  = 4096;
constexpr int RANKC  = 12;
constexpr float SCAL = 16.0f / 12.0f;
constexpr int MTOT   = 4 * 4096;   // B*S = 16384
constexpr int NT     = IN_F / 32;  // 128 K-tiles (BK=32)

// prep kernel grid split
constexpr int CVT_BLOCKS  = (MTOT * IN_F) / (256 * 8);     // 32768
constexpr int FOLD_BLOCKS = (OUT_F * IN_F) / (256 * 4);    // 16384

typedef __attribute__((address_space(1))) const unsigned int uint_g;
typedef __attribute__((address_space(3))) unsigned int uint_l;

__device__ __forceinline__ void gload_lds16(const void* g, void* l) {
    __builtin_amdgcn_global_load_lds((uint_g*)(uintptr_t)g,
                                     (uint_l*)(uintptr_t)l,
                                     16, 0, 0);
}

// ---------------------------------------------------------------------------
// Kernel 1 (merged prep):
//   blocks [0, CVT_BLOCKS):      x fp32 -> bf16 (8 elems/thread)
//   blocks [CVT_BLOCKS, +FOLD):  Wb = bf16(W + SCAL * (P*sigma) Q^T)  (4/thr)
// ---------------------------------------------------------------------------
__global__ __launch_bounds__(256) void prep_kernel(
    const float* __restrict__ X,  bf16_t* __restrict__ Xb,
    const float* __restrict__ W,  const float* __restrict__ P,
    const float* __restrict__ sg, const float* __restrict__ Q,
    bf16_t* __restrict__ Wb)
{
    if (blockIdx.x < CVT_BLOCKS) {
        const size_t base = ((size_t)blockIdx.x * 256 + threadIdx.x) * 8;
        const float4 a = *reinterpret_cast<const float4*>(X + base);
        const float4 b = *reinterpret_cast<const float4*>(X + base + 4);
        bf16x8 ob;
        ob[0] = (bf16_t)a.x; ob[1] = (bf16_t)a.y; ob[2] = (bf16_t)a.z; ob[3] = (bf16_t)a.w;
        ob[4] = (bf16_t)b.x; ob[5] = (bf16_t)b.y; ob[6] = (bf16_t)b.z; ob[7] = (bf16_t)b.w;
        *reinterpret_cast<bf16x8*>(Xb + base) = ob;
    } else {
        const int t    = (blockIdx.x - CVT_BLOCKS) * 256 + threadIdx.x;
        const int base = t * 4;
        const int o    = base >> 12;            // IN_F = 4096 = 2^12
        const int i0   = base & (IN_F - 1);

        float psig[RANKC];
#pragma unroll
        for (int r = 0; r < RANKC; ++r)
            psig[r] = P[o * RANKC + r] * sg[r] * SCAL;

        const float4 w = *reinterpret_cast<const float4*>(W + base);
        float out[4] = {w.x, w.y, w.z, w.w};
#pragma unroll
        for (int j = 0; j < 4; ++j) {
            const float* q = Q + (size_t)(i0 + j) * RANKC;
            float d = 0.0f;
#pragma unroll
            for (int r = 0; r < RANKC; ++r) d += psig[r] * q[r];
            out[j] += d;
        }
        bf16x4 ob;
#pragma unroll
        for (int j = 0; j < 4; ++j) ob[j] = (bf16_t)out[j];
        *reinterpret_cast<bf16x4*>(Wb + base) = ob;
    }
}

// ---------------------------------------------------------------------------
// Kernel 2: 256x256 GEMM, BK=32, 2-phase/K-tile, 80 KiB LDS -> 2 blocks/CU.
//
// Buffers: A triple (a0,a1,a2 = Abuf[t%3]), B double (b0,b1 = Bbuf[t&1]).
// Swizzle (64 B rows, 4x16B chunks): logical chunk c of row r stored at slot
// c ^ ((r>>1)&3). Fragment reads (16 rows/quarter-wave) hit each bank-group
// exactly 2x (free 2-way). gload_lds dest linear; source inverse-permuted.
//
// Per K-tile t (2 phases, 16 MFMA each, 1 barrier each):
//  pA: stage B(t+2)->Bbuf[t&1] x2, A(t+2)->Abuf[(t+2)%3] x2;
//      read afB <- A(t).mh1; MM(afA, bq_cur, mh0); VMW(4); LGKM0; BAR
//  pB: read afA <- A(t+1).mh0, bq_next <- B(t+1); MM(afB, bq_cur, mh1);
//      LGKM0; BAR
// VMW(4) at pA-end drains B(t+1)+A(t+1) (read at pB(t)/pA(t+1) heads, both
// >=1 barrier later); queue 8->4, never 0; 2-phase staging lead.
// RACE-SAFE: every phase ends lgkmcnt(0)+BAR, so a region's last ds_read is
// complete one barrier before any DMA overwrite:
//   Bbuf[t&1] (B(t)): last read pB(t-1) head, overwritten pA(t)   [1 BAR]
//   Abuf[(t+2)%3] (A(t-1)): last read pA(t-1) head, overwritten pA(t) [2 BAR]
// Clamped tail stages re-stage tile NT-1 data into dead regions; VMW counts
// preserved; junk prefetches unused.
// ---------------------------------------------------------------------------
__device__ __forceinline__ void stage128(const bf16_t* __restrict__ g, size_t grow0,
                                         bf16_t* lt, int ldrow0, int kt, int tid)
{
    const int rr = tid >> 2;                        // 0..127 within region
    const int cs = (tid & 3) ^ ((rr >> 1) & 3);     // inverse-swizzled src chunk
    const bf16_t* src = g + (grow0 + (size_t)(ldrow0 + rr)) * IN_F + kt * 32 + cs * 8;
    gload_lds16(src, lt + ldrow0 * 32 + tid * 8);   // linear LDS dest
}

#define VMW(N) asm volatile("s_waitcnt vmcnt(" #N ")" ::: "memory")
#define LGKM0  asm volatile("s_waitcnt lgkmcnt(0)" ::: "memory")
#define BAR    __builtin_amdgcn_s_barrier()
#define SB     __builtin_amdgcn_sched_barrier(0)

#define RD_A32(DST, BUF, MH) do {                                               \
    _Pragma("unroll")                                                           \
    for (int m_ = 0; m_ < 4; ++m_) {                                            \
        const int row_ = wm * 128 + (MH) * 64 + m_ * 16 + lr;                   \
        DST[m_] = *(const bf16x8*)&BUF[row_ * 32 + ((hi ^ ((row_ >> 1) & 3)) * 8)]; \
    }                                                                           \
} while (0)

#define RD_B32(DST, BUF) do {                                                   \
    _Pragma("unroll")                                                           \
    for (int n_ = 0; n_ < 4; ++n_) {                                            \
        const int row_ = wn * 64 + n_ * 16 + lr;                                \
        DST[n_] = *(const bf16x8*)&BUF[row_ * 32 + ((hi ^ ((row_ >> 1) & 3)) * 8)]; \
    }                                                                           \
} while (0)

#define MM32(AF, BQ, MH) do {                                                   \
    __builtin_amdgcn_s_setprio(1);                                              \
    _Pragma("unroll")                                                           \
    for (int m_ = 0; m_ < 4; ++m_)                                              \
        _Pragma("unroll")                                                       \
        for (int n_ = 0; n_ < 4; ++n_)                                          \
            acc[(MH) * 4 + m_][n_] = __builtin_amdgcn_mfma_f32_16x16x32_bf16(   \
                AF[m_], BQ[n_], acc[(MH) * 4 + m_][n_], 0, 0, 0);               \
    __builtin_amdgcn_s_setprio(0);                                              \
} while (0)

#define TILE(T, A0_, A1_, A2_, B0_, B1_, BQC, BQN) do {                         \
    const int t2_ = ((T) + 2 < NT) ? (T) + 2 : NT - 1;                          \
    /* pA: consume (afA, BQC) = A(T).mh0 x B(T) */                              \
    stage128(Bm, bcol, B0_, 0,   t2_, tid);                                     \
    stage128(Bm, bcol, B0_, 128, t2_, tid);                                     \
    stage128(Am, brow, A2_, 0,   t2_, tid);                                     \
    stage128(Am, brow, A2_, 128, t2_, tid);                                     \
    RD_A32(afB, A0_, 1);                                                        \
    MM32(afA, BQC, 0);                                                          \
    VMW(4);                                                                     \
    LGKM0; BAR; SB;                                                             \
    /* pB: consume (afB, BQC) = A(T).mh1 x B(T); prefetch next tile */          \
    RD_A32(afA, A1_, 0);                                                        \
    RD_B32(BQN, B1_);                                                           \
    MM32(afB, BQC, 1);                                                          \
    LGKM0; BAR; SB;                                                             \
} while (0)

__global__ __launch_bounds__(512, 4) void gemm256_kernel(
    const bf16_t* __restrict__ Am,   // [MTOT, IN_F]
    const bf16_t* __restrict__ Bm,   // [OUT_F, IN_F]
    float* __restrict__ C)           // [MTOT, OUT_F]
{
    __shared__ bf16_t a0[256 * 32], a1[256 * 32], a2[256 * 32];  // 48 KiB
    __shared__ bf16_t b0[256 * 32], b1[256 * 32];                // 32 KiB

    const int tid  = threadIdx.x;
    const int lane = tid & 63;
    const int lr   = lane & 15;
    const int hi   = lane >> 4;
    const int wave = tid >> 6;
    const int wm   = wave >> 2;      // 0..1
    const int wn   = wave & 3;       // 0..3

    // XCD-aware bijective swizzle (nwg = 1024, % 8 == 0)
    const int bid = blockIdx.x;
    const int swz = (bid & 7) * 128 + (bid >> 3);
    const size_t brow = (size_t)(swz >> 4) * 256;   // 64 row-blocks
    const size_t bcol = (size_t)(swz & 15) * 256;   // 16 col-blocks

    f32x4 acc[8][4];
#pragma unroll
    for (int i = 0; i < 8; ++i)
#pragma unroll
        for (int n = 0; n < 4; ++n)
#pragma unroll
            for (int q = 0; q < 4; ++q) acc[i][n][q] = 0.0f;

    bf16x8 bqE[4], bqO[4];
    bf16x8 afA[4], afB[4];

    // Prologue (FIFO: B(0)2, A(0)2, B(1)2, A(1)2):
    stage128(Bm, bcol, b0, 0,   0, tid);
    stage128(Bm, bcol, b0, 128, 0, tid);
    stage128(Am, brow, a0, 0,   0, tid);
    stage128(Am, brow, a0, 128, 0, tid);
    stage128(Bm, bcol, b1, 0,   1, tid);
    stage128(Bm, bcol, b1, 128, 1, tid);
    stage128(Am, brow, a1, 0,   1, tid);
    stage128(Am, brow, a1, 128, 1, tid);
    VMW(4);                 // drain B(0)+A(0); keep [B(1)2, A(1)2] in flight
    BAR; SB;
    RD_A32(afA, a0, 0);     // A(0).mh0
    RD_B32(bqE, b0);        // B(0)
    LGKM0; BAR; SB;         // reads complete before pA(0)'s DMA into b0/a2

    for (int tt = 0; tt < NT - 2; tt += 6) {
        TILE(tt + 0, a0, a1, a2, b0, b1, bqE, bqO);
        TILE(tt + 1, a1, a2, a0, b1, b0, bqO, bqE);
        TILE(tt + 2, a2, a0, a1, b0, b1, bqE, bqO);
        TILE(tt + 3, a0, a1, a2, b1, b0, bqO, bqE);
        TILE(tt + 4, a1, a2, a0, b0, b1, bqE, bqO);
        TILE(tt + 5, a2, a0, a1, b1, b0, bqO, bqE);
    }
    // tail: tiles 126, 127 (rotation continues; stages clamp to NT-1)
    TILE(126, a0, a1, a2, b0, b1, bqE, bqO);
    TILE(127, a1, a2, a0, b1, b0, bqO, bqE);

    // Epilogue: D col = lane&15, row = (lane>>4)*4 + reg  [m89-verified]
    const size_t r0 = brow + (size_t)wm * 128 + hi * 4;
    const size_t c0 = bcol + (size_t)wn * 64 + lr;
#pragma unroll
    for (int mi = 0; mi < 8; ++mi)
#pragma unroll
        for (int n = 0; n < 4; ++n)
#pragma unroll
            for (int q = 0; q < 4; ++q)
                C[(r0 + mi * 16 + q) * OUT_F + c0 + n * 16] = acc[mi][n][q];
}

// ---------------------------------------------------------------------------
extern "C" void kernel_launch(void* const* d_in, const int* in_sizes, int n_in,
                              void* d_out, int out_size, void* d_ws, size_t ws_size,
                              hipStream_t stream)
{
    const float* x      = (const float*)d_in[0];
    const float* weight = (const float*)d_in[1];
    const float* loraP  = (const float*)d_in[2];
    const float* sigma  = (const float*)d_in[3];
    const float* loraQ  = (const float*)d_in[4];
    float* out = (float*)d_out;

    bf16_t* Wb = (bf16_t*)d_ws;                                      // 32 MiB
    bf16_t* Xb = (bf16_t*)((char*)d_ws + (size_t)OUT_F * IN_F * 2);  // 128 MiB

    prep_kernel<<<CVT_BLOCKS + FOLD_BLOCKS, 256, 0, stream>>>(
        x, Xb, weight, loraP, sigma, loraQ, Wb);

    gemm256_kernel<<<(MTOT / 256) * (OUT_F / 256), 512, 0, stream>>>(Xb, Wb, out);
}

// Round 11
// 607.726 us; speedup vs baseline: 12.1816x; 12.1816x over previous
//
#include <hip/hip_runtime.h>
#include <hip/hip_bf16.h>
#include <stdint.h>

typedef __bf16 bf16_t;
typedef __attribute__((ext_vector_type(8))) __bf16 bf16x8;
typedef __attribute__((ext_vector_type(4))) __bf16 bf16x4;
typedef __attribute__((ext_vector_type(4))) float f32x4;

constexpr int IN_F   = 4096;
constexpr int OUT_F  = 4096;
constexpr int RANKC  = 12;
constexpr float SCAL = 16.0f / 12.0f;
constexpr int MTOT   = 4 * 4096;   // B*S = 16384
constexpr int NT     = IN_F / 64;  // 64 K-tiles

// prep kernel grid split
constexpr int CVT_BLOCKS  = (MTOT * IN_F) / (256 * 8);     // 32768
constexpr int FOLD_BLOCKS = (OUT_F * IN_F) / (256 * 4);    // 16384

typedef __attribute__((address_space(1))) const unsigned int uint_g;
typedef __attribute__((address_space(3))) unsigned int uint_l;

__device__ __forceinline__ void gload_lds16(const void* g, void* l) {
    __builtin_amdgcn_global_load_lds((uint_g*)(uintptr_t)g,
                                     (uint_l*)(uintptr_t)l,
                                     16, 0, 0);
}

// ---------------------------------------------------------------------------
// Kernel 1 (merged prep):
//   blocks [0, CVT_BLOCKS):      x fp32 -> bf16 (8 elems/thread)
//   blocks [CVT_BLOCKS, +FOLD):  Wb = bf16(W + SCAL * (P*sigma) Q^T)  (4/thr)
// ---------------------------------------------------------------------------
__global__ __launch_bounds__(256) void prep_kernel(
    const float* __restrict__ X,  bf16_t* __restrict__ Xb,
    const float* __restrict__ W,  const float* __restrict__ P,
    const float* __restrict__ sg, const float* __restrict__ Q,
    bf16_t* __restrict__ Wb)
{
    if (blockIdx.x < CVT_BLOCKS) {
        const size_t base = ((size_t)blockIdx.x * 256 + threadIdx.x) * 8;
        const float4 a = *reinterpret_cast<const float4*>(X + base);
        const float4 b = *reinterpret_cast<const float4*>(X + base + 4);
        bf16x8 ob;
        ob[0] = (bf16_t)a.x; ob[1] = (bf16_t)a.y; ob[2] = (bf16_t)a.z; ob[3] = (bf16_t)a.w;
        ob[4] = (bf16_t)b.x; ob[5] = (bf16_t)b.y; ob[6] = (bf16_t)b.z; ob[7] = (bf16_t)b.w;
        *reinterpret_cast<bf16x8*>(Xb + base) = ob;
    } else {
        const int t    = (blockIdx.x - CVT_BLOCKS) * 256 + threadIdx.x;
        const int base = t * 4;
        const int o    = base >> 12;            // IN_F = 4096 = 2^12
        const int i0   = base & (IN_F - 1);

        float psig[RANKC];
#pragma unroll
        for (int r = 0; r < RANKC; ++r)
            psig[r] = P[o * RANKC + r] * sg[r] * SCAL;

        const float4 w = *reinterpret_cast<const float4*>(W + base);
        float out[4] = {w.x, w.y, w.z, w.w};
#pragma unroll
        for (int j = 0; j < 4; ++j) {
            const float* q = Q + (size_t)(i0 + j) * RANKC;
            float d = 0.0f;
#pragma unroll
            for (int r = 0; r < RANKC; ++r) d += psig[r] * q[r];
            out[j] += d;
        }
        bf16x4 ob;
#pragma unroll
        for (int j = 0; j < 4; ++j) ob[j] = (bf16_t)out[j];
        *reinterpret_cast<bf16x4*>(Wb + base) = ob;
    }
}

// ---------------------------------------------------------------------------
// Kernel 2: 256x256 4-phase pipelined GEMM (verified best: R8 config).
// 1 block/CU is REGISTER-MANDATORY here: acc = 128 AGPR + 128 VGPR = 256
// unified regs = exactly the 2-waves/EU budget. (R10: launch_bounds(512,4)
// forced a 128-reg budget -> accumulator spilled to scratch -> 16x slower.)
//
// Waits (hazard-traced, 2 per K-tile; queue 4->6->8->2->4, never 0):
//   p1-end VMW(4): drains A-H1(t)   [staged p3(t-1); read p2/p3 heads]
//   p3-end VMW(2): drains A-H0(t+1)+B(t+1) [read p4 head]
// RACE-SAFE rule: every phase-head ds_read targets a region drained by a VMW
// in an EARLIER phase followed by a barrier (all-waves guarantee).
// ---------------------------------------------------------------------------
__device__ __forceinline__ void stage64(const bf16_t* __restrict__ g, size_t grow0,
                                        bf16_t* lt, int ldrow0, int kt, int tid)
{
    const int rr  = tid >> 3;                       // 0..63 within region
    const int c16 = (tid & 7) ^ (rr & 7);           // inverse-swizzled source chunk
    const bf16_t* src = g + (grow0 + (size_t)(ldrow0 + rr)) * IN_F + kt * 64 + c16 * 8;
    gload_lds16(src, lt + ldrow0 * 64 + tid * 8);   // linear LDS dest
}

#define VMW(N) asm volatile("s_waitcnt vmcnt(" #N ")" ::: "memory")
#define BAR    __builtin_amdgcn_s_barrier()
#define SB     __builtin_amdgcn_sched_barrier(0)

#define RD_A(DST, BUF, MH, KK) do {                                             \
    _Pragma("unroll")                                                           \
    for (int m_ = 0; m_ < 4; ++m_)                                              \
        DST[m_] = *(const bf16x8*)&BUF[(wm * 128 + (MH) * 64 + m_ * 16 + lr) * 64 \
                                       + (((KK) * 4 + hi) ^ (lr & 7)) * 8];     \
} while (0)

#define RD_B(BUF, KK) do {                                                      \
    _Pragma("unroll")                                                           \
    for (int n_ = 0; n_ < 4; ++n_)                                              \
        bq[KK][n_] = *(const bf16x8*)&BUF[(wn * 64 + n_ * 16 + lr) * 64         \
                                       + (((KK) * 4 + hi) ^ (lr & 7)) * 8];     \
} while (0)

#define MM(AF, KK, MH) do {                                                     \
    __builtin_amdgcn_s_setprio(1);                                              \
    _Pragma("unroll")                                                           \
    for (int m_ = 0; m_ < 4; ++m_)                                              \
        _Pragma("unroll")                                                       \
        for (int n_ = 0; n_ < 4; ++n_)                                          \
            acc[(MH) * 4 + m_][n_] = __builtin_amdgcn_mfma_f32_16x16x32_bf16(   \
                AF[m_], bq[KK][n_], acc[(MH) * 4 + m_][n_], 0, 0, 0);           \
    __builtin_amdgcn_s_setprio(0);                                              \
} while (0)

#define TILE(T, CA_, CB_, NA_, NB_) do {                                        \
    const int t1_ = ((T) + 1 < NT) ? (T) + 1 : NT - 1;                          \
    const int t2_ = ((T) + 2 < NT) ? (T) + 2 : NT - 1;                          \
    /* p1: consume (afA,bq0); prefetch (afB,bq1) for p2 */                      \
    stage64(Bm, bcol, NB_, 0,   t1_, tid);                                      \
    stage64(Bm, bcol, NB_, 64,  t1_, tid);                                      \
    RD_A(afB, CA_, 0, 1);                                                       \
    RD_B(CB_, 1);                                                               \
    MM(afA, 0, 0);                                                              \
    VMW(4);                                                                     \
    BAR; SB;                                                                    \
    /* p2: consume (afB,bq1); prefetch afA for p3 */                            \
    stage64(Bm, bcol, NB_, 128, t1_, tid);                                      \
    stage64(Bm, bcol, NB_, 192, t1_, tid);                                      \
    RD_A(afA, CA_, 1, 0);                                                       \
    MM(afB, 1, 0);                                                              \
    BAR; SB;                                                                    \
    /* p3: consume (afA,bq0); prefetch afB for p4 */                            \
    stage64(Am, brow, NA_, 64,  t1_, tid);                                      \
    stage64(Am, brow, NA_, 192, t1_, tid);                                      \
    RD_A(afB, CA_, 1, 1);                                                       \
    MM(afA, 0, 1);                                                              \
    VMW(2);                                                                     \
    BAR; SB;                                                                    \
    /* p4: consume (afB,bq1); prefetch (afA,bq0) for p1(t+1) from next bufs */  \
    stage64(Am, brow, CA_, 0,   t2_, tid);                                      \
    stage64(Am, brow, CA_, 128, t2_, tid);                                      \
    RD_A(afA, NA_, 0, 0);                                                       \
    RD_B(NB_, 0);                                                               \
    MM(afB, 1, 1);                                                              \
    BAR; SB;                                                                    \
} while (0)

__global__ __launch_bounds__(512, 2) void gemm256_kernel(
    const bf16_t* __restrict__ Am,   // [MTOT, IN_F]
    const bf16_t* __restrict__ Bm,   // [OUT_F, IN_F]
    float* __restrict__ C)           // [MTOT, OUT_F]
{
    __shared__ bf16_t sA0[256 * 64], sB0[256 * 64], sA1[256 * 64], sB1[256 * 64];

    const int tid  = threadIdx.x;
    const int lane = tid & 63;
    const int lr   = lane & 15;
    const int hi   = lane >> 4;
    const int wave = tid >> 6;
    const int wm   = wave >> 2;      // 0..1
    const int wn   = wave & 3;       // 0..3

    // XCD-aware bijective swizzle (nwg = 1024, % 8 == 0)
    const int bid = blockIdx.x;
    const int swz = (bid & 7) * 128 + (bid >> 3);
    const size_t brow = (size_t)(swz >> 4) * 256;   // 64 row-blocks
    const size_t bcol = (size_t)(swz & 15) * 256;   // 16 col-blocks

    f32x4 acc[8][4];
#pragma unroll
    for (int i = 0; i < 8; ++i)
#pragma unroll
        for (int n = 0; n < 4; ++n)
#pragma unroll
            for (int q = 0; q < 4; ++q) acc[i][n][q] = 0.0f;

    bf16x8 bq[2][4];
    bf16x8 afA[4], afB[4];

    // Prologue: drain A-H0(0)+B(0) with VMW(4); leave [A-H1(0)2, A-H0(1)2]
    // in flight -- matches the steady-state p1 entry queue.
    stage64(Am, brow, sA0, 0,   0, tid);   // A-H0(0)
    stage64(Am, brow, sA0, 128, 0, tid);
    stage64(Bm, bcol, sB0, 0,   0, tid);   // B(0)
    stage64(Bm, bcol, sB0, 64,  0, tid);
    stage64(Bm, bcol, sB0, 128, 0, tid);
    stage64(Bm, bcol, sB0, 192, 0, tid);
    stage64(Am, brow, sA0, 64,  0, tid);   // A-H1(0)
    stage64(Am, brow, sA0, 192, 0, tid);
    stage64(Am, brow, sA1, 0,   1, tid);   // A-H0(1)
    stage64(Am, brow, sA1, 128, 1, tid);
    VMW(4);
    BAR; SB;
    // initial fragments for p1(0)'s MFMA (regions drained above, post-BAR)
    RD_A(afA, sA0, 0, 0);
    RD_B(sB0, 0);

    for (int tt = 0; tt < NT; tt += 2) {
        TILE(tt,     sA0, sB0, sA1, sB1);
        TILE(tt + 1, sA1, sB1, sA0, sB0);
    }

    // Epilogue: D col = lane&15, row = (lane>>4)*4 + reg  [m89-verified]
    const size_t r0 = brow + (size_t)wm * 128 + hi * 4;
    const size_t c0 = bcol + (size_t)wn * 64 + lr;
#pragma unroll
    for (int mi = 0; mi < 8; ++mi)
#pragma unroll
        for (int n = 0; n < 4; ++n)
#pragma unroll
            for (int q = 0; q < 4; ++q)
                C[(r0 + mi * 16 + q) * OUT_F + c0 + n * 16] = acc[mi][n][q];
}

// ---------------------------------------------------------------------------
extern "C" void kernel_launch(void* const* d_in, const int* in_sizes, int n_in,
                              void* d_out, int out_size, void* d_ws, size_t ws_size,
                              hipStream_t stream)
{
    const float* x      = (const float*)d_in[0];
    const float* weight = (const float*)d_in[1];
    const float* loraP  = (const float*)d_in[2];
    const float* sigma  = (const float*)d_in[3];
    const float* loraQ  = (const float*)d_in[4];
    float* out = (float*)d_out;

    bf16_t* Wb = (bf16_t*)d_ws;                                      // 32 MiB
    bf16_t* Xb = (bf16_t*)((char*)d_ws + (size_t)OUT_F * IN_F * 2);  // 128 MiB

    prep_kernel<<<CVT_BLOCKS + FOLD_BLOCKS, 256, 0, stream>>>(
        x, Xb, weight, loraP, sigma, loraQ, Wb);

    gemm256_kernel<<<(MTOT / 256) * (OUT_F / 256), 512, 0, stream>>>(Xb, Wb, out);
}

// Round 12
// 598.889 us; speedup vs baseline: 12.3614x; 1.0148x over previous
//
#include <hip/hip_runtime.h>
#include <hip/hip_bf16.h>
#include <stdint.h>

typedef __bf16 bf16_t;
typedef __attribute__((ext_vector_type(8))) __bf16 bf16x8;
typedef __attribute__((ext_vector_type(4))) __bf16 bf16x4;
typedef __attribute__((ext_vector_type(4))) float f32x4;

constexpr int IN_F   = 4096;
constexpr int OUT_F  = 4096;
constexpr int RANKC  = 12;
constexpr float SCAL = 16.0f / 12.0f;
constexpr int MTOT   = 4 * 4096;   // B*S = 16384
constexpr int NT     = IN_F / 64;  // 64 K-tiles

// prep kernel grid split
constexpr int CVT_BLOCKS  = (MTOT * IN_F) / (256 * 8);     // 32768
constexpr int FOLD_BLOCKS = (OUT_F * IN_F) / (256 * 4);    // 16384

typedef __attribute__((address_space(1))) const unsigned int uint_g;
typedef __attribute__((address_space(3))) unsigned int uint_l;

__device__ __forceinline__ void gload_lds16(const void* g, void* l) {
    __builtin_amdgcn_global_load_lds((uint_g*)(uintptr_t)g,
                                     (uint_l*)(uintptr_t)l,
                                     16, 0, 0);
}

// ---------------------------------------------------------------------------
// Kernel 1 (merged prep):
//   blocks [0, CVT_BLOCKS):      x fp32 -> bf16 (8 elems/thread)
//   blocks [CVT_BLOCKS, +FOLD):  Wb = bf16(W + SCAL * (P*sigma) Q^T)  (4/thr)
// ---------------------------------------------------------------------------
__global__ __launch_bounds__(256) void prep_kernel(
    const float* __restrict__ X,  bf16_t* __restrict__ Xb,
    const float* __restrict__ W,  const float* __restrict__ P,
    const float* __restrict__ sg, const float* __restrict__ Q,
    bf16_t* __restrict__ Wb)
{
    if (blockIdx.x < CVT_BLOCKS) {
        const size_t base = ((size_t)blockIdx.x * 256 + threadIdx.x) * 8;
        const float4 a = *reinterpret_cast<const float4*>(X + base);
        const float4 b = *reinterpret_cast<const float4*>(X + base + 4);
        bf16x8 ob;
        ob[0] = (bf16_t)a.x; ob[1] = (bf16_t)a.y; ob[2] = (bf16_t)a.z; ob[3] = (bf16_t)a.w;
        ob[4] = (bf16_t)b.x; ob[5] = (bf16_t)b.y; ob[6] = (bf16_t)b.z; ob[7] = (bf16_t)b.w;
        *reinterpret_cast<bf16x8*>(Xb + base) = ob;
    } else {
        const int t    = (blockIdx.x - CVT_BLOCKS) * 256 + threadIdx.x;
        const int base = t * 4;
        const int o    = base >> 12;            // IN_F = 4096 = 2^12
        const int i0   = base & (IN_F - 1);

        float psig[RANKC];
#pragma unroll
        for (int r = 0; r < RANKC; ++r)
            psig[r] = P[o * RANKC + r] * sg[r] * SCAL;

        const float4 w = *reinterpret_cast<const float4*>(W + base);
        float out[4] = {w.x, w.y, w.z, w.w};
#pragma unroll
        for (int j = 0; j < 4; ++j) {
            const float* q = Q + (size_t)(i0 + j) * RANKC;
            float d = 0.0f;
#pragma unroll
            for (int r = 0; r < RANKC; ++r) d += psig[r] * q[r];
            out[j] += d;
        }
        bf16x4 ob;
#pragma unroll
        for (int j = 0; j < 4; ++j) ob[j] = (bf16_t)out[j];
        *reinterpret_cast<bf16x4*>(Wb + base) = ob;
    }
}

// ---------------------------------------------------------------------------
// Kernel 2: 256x256 4-phase pipelined GEMM -- R8 skeleton with RELAXED SYNC:
// barriers only at p1-end (VMW(4)+BAR) and p3-end (VMW(2)+BAR); p2-end and
// p4-end barriers REMOVED (waves may drift within {p2,p3} and {p4,p1'}).
//
// Publish safety (DMA->read): unchanged from R8 --
//   p1-end VMW(4)+BAR drains A-H1(t)          [read p2/p3 heads]
//   p3-end VMW(2)+BAR drains A-H0(t+1)+B(t+1) [read p4/p1' heads]
//   queue 4->6->8->2->4, never 0.
// WAR safety (read->DMA overwrite), traced per region under drift:
//   B(t)     last read p1(t) head, MFMA-drained p2(t); overwritten p1(t+1)
//            -> p3(t)-end BAR between.
//   A-H0(t)  last read p1(t) head (kk1), drained p2(t); overwritten p4(t)
//            -> p3(t)-end BAR between.
//   A-H1(t)  last read p3(t) head (kk1), drained p4(t); overwritten p3(t+1)
//            -> p1(t+1)-end BAR between.
//   NA_/NB_ (t+1 regions) symmetric, >=1 retained BAR in every case.
// Drift windows only touch disjoint buffers (checked p4(t) vs p1(t+1),
// p2 vs p3). 1 block/CU is register-mandatory (R10: acc=128 AGPR alone).
// ---------------------------------------------------------------------------
__device__ __forceinline__ void stage64(const bf16_t* __restrict__ g, size_t grow0,
                                        bf16_t* lt, int ldrow0, int kt, int tid)
{
    const int rr  = tid >> 3;                       // 0..63 within region
    const int c16 = (tid & 7) ^ (rr & 7);           // inverse-swizzled source chunk
    const bf16_t* src = g + (grow0 + (size_t)(ldrow0 + rr)) * IN_F + kt * 64 + c16 * 8;
    gload_lds16(src, lt + ldrow0 * 64 + tid * 8);   // linear LDS dest
}

#define VMW(N) asm volatile("s_waitcnt vmcnt(" #N ")" ::: "memory")
#define BAR    __builtin_amdgcn_s_barrier()
#define SB     __builtin_amdgcn_sched_barrier(0)

#define RD_A(DST, BUF, MH, KK) do {                                             \
    _Pragma("unroll")                                                           \
    for (int m_ = 0; m_ < 4; ++m_)                                              \
        DST[m_] = *(const bf16x8*)&BUF[(wm * 128 + (MH) * 64 + m_ * 16 + lr) * 64 \
                                       + (((KK) * 4 + hi) ^ (lr & 7)) * 8];     \
} while (0)

#define RD_B(BUF, KK) do {                                                      \
    _Pragma("unroll")                                                           \
    for (int n_ = 0; n_ < 4; ++n_)                                              \
        bq[KK][n_] = *(const bf16x8*)&BUF[(wn * 64 + n_ * 16 + lr) * 64         \
                                       + (((KK) * 4 + hi) ^ (lr & 7)) * 8];     \
} while (0)

#define MM(AF, KK, MH) do {                                                     \
    __builtin_amdgcn_s_setprio(1);                                              \
    _Pragma("unroll")                                                           \
    for (int m_ = 0; m_ < 4; ++m_)                                              \
        _Pragma("unroll")                                                       \
        for (int n_ = 0; n_ < 4; ++n_)                                          \
            acc[(MH) * 4 + m_][n_] = __builtin_amdgcn_mfma_f32_16x16x32_bf16(   \
                AF[m_], bq[KK][n_], acc[(MH) * 4 + m_][n_], 0, 0, 0);           \
    __builtin_amdgcn_s_setprio(0);                                              \
} while (0)

#define TILE(T, CA_, CB_, NA_, NB_) do {                                        \
    const int t1_ = ((T) + 1 < NT) ? (T) + 1 : NT - 1;                          \
    const int t2_ = ((T) + 2 < NT) ? (T) + 2 : NT - 1;                          \
    /* p1: consume (afA,bq0); prefetch (afB,bq1) for p2 */                      \
    stage64(Bm, bcol, NB_, 0,   t1_, tid);                                      \
    stage64(Bm, bcol, NB_, 64,  t1_, tid);                                      \
    RD_A(afB, CA_, 0, 1);                                                       \
    RD_B(CB_, 1);                                                               \
    MM(afA, 0, 0);                                                              \
    VMW(4);                                                                     \
    BAR; SB;                                                                    \
    /* p2: consume (afB,bq1); prefetch afA for p3  [no barrier at end] */       \
    stage64(Bm, bcol, NB_, 128, t1_, tid);                                      \
    stage64(Bm, bcol, NB_, 192, t1_, tid);                                      \
    RD_A(afA, CA_, 1, 0);                                                       \
    MM(afB, 1, 0);                                                              \
    SB;                                                                         \
    /* p3: consume (afA,bq0); prefetch afB for p4 */                            \
    stage64(Am, brow, NA_, 64,  t1_, tid);                                      \
    stage64(Am, brow, NA_, 192, t1_, tid);                                      \
    RD_A(afB, CA_, 1, 1);                                                       \
    MM(afA, 0, 1);                                                              \
    VMW(2);                                                                     \
    BAR; SB;                                                                    \
    /* p4: consume (afB,bq1); prefetch (afA,bq0) from next bufs                 \
       [no barrier at end] */                                                   \
    stage64(Am, brow, CA_, 0,   t2_, tid);                                      \
    stage64(Am, brow, CA_, 128, t2_, tid);                                      \
    RD_A(afA, NA_, 0, 0);                                                       \
    RD_B(NB_, 0);                                                               \
    MM(afB, 1, 1);                                                              \
    SB;                                                                         \
} while (0)

__global__ __launch_bounds__(512, 2) void gemm256_kernel(
    const bf16_t* __restrict__ Am,   // [MTOT, IN_F]
    const bf16_t* __restrict__ Bm,   // [OUT_F, IN_F]
    float* __restrict__ C)           // [MTOT, OUT_F]
{
    __shared__ bf16_t sA0[256 * 64], sB0[256 * 64], sA1[256 * 64], sB1[256 * 64];

    const int tid  = threadIdx.x;
    const int lane = tid & 63;
    const int lr   = lane & 15;
    const int hi   = lane >> 4;
    const int wave = tid >> 6;
    const int wm   = wave >> 2;      // 0..1
    const int wn   = wave & 3;       // 0..3

    // XCD-aware bijective swizzle (nwg = 1024, % 8 == 0)
    const int bid = blockIdx.x;
    const int swz = (bid & 7) * 128 + (bid >> 3);
    const size_t brow = (size_t)(swz >> 4) * 256;   // 64 row-blocks
    const size_t bcol = (size_t)(swz & 15) * 256;   // 16 col-blocks

    f32x4 acc[8][4];
#pragma unroll
    for (int i = 0; i < 8; ++i)
#pragma unroll
        for (int n = 0; n < 4; ++n)
#pragma unroll
            for (int q = 0; q < 4; ++q) acc[i][n][q] = 0.0f;

    bf16x8 bq[2][4];
    bf16x8 afA[4], afB[4];

    // Prologue: drain A-H0(0)+B(0) with VMW(4); leave [A-H1(0)2, A-H0(1)2]
    // in flight -- matches the steady-state p1 entry queue.
    stage64(Am, brow, sA0, 0,   0, tid);   // A-H0(0)
    stage64(Am, brow, sA0, 128, 0, tid);
    stage64(Bm, bcol, sB0, 0,   0, tid);   // B(0)
    stage64(Bm, bcol, sB0, 64,  0, tid);
    stage64(Bm, bcol, sB0, 128, 0, tid);
    stage64(Bm, bcol, sB0, 192, 0, tid);
    stage64(Am, brow, sA0, 64,  0, tid);   // A-H1(0)
    stage64(Am, brow, sA0, 192, 0, tid);
    stage64(Am, brow, sA1, 0,   1, tid);   // A-H0(1)
    stage64(Am, brow, sA1, 128, 1, tid);
    VMW(4);
    BAR; SB;
    // initial fragments for p1(0)'s MFMA (regions drained above, post-BAR)
    RD_A(afA, sA0, 0, 0);
    RD_B(sB0, 0);

    for (int tt = 0; tt < NT; tt += 2) {
        TILE(tt,     sA0, sB0, sA1, sB1);
        TILE(tt + 1, sA1, sB1, sA0, sB0);
    }

    // Epilogue: D col = lane&15, row = (lane>>4)*4 + reg  [m89-verified]
    const size_t r0 = brow + (size_t)wm * 128 + hi * 4;
    const size_t c0 = bcol + (size_t)wn * 64 + lr;
#pragma unroll
    for (int mi = 0; mi < 8; ++mi)
#pragma unroll
        for (int n = 0; n < 4; ++n)
#pragma unroll
            for (int q = 0; q < 4; ++q)
                C[(r0 + mi * 16 + q) * OUT_F + c0 + n * 16] = acc[mi][n][q];
}

// ---------------------------------------------------------------------------
extern "C" void kernel_launch(void* const* d_in, const int* in_sizes, int n_in,
                              void* d_out, int out_size, void* d_ws, size_t ws_size,
                              hipStream_t stream)
{
    const float* x      = (const float*)d_in[0];
    const float* weight = (const float*)d_in[1];
    const float* loraP  = (const float*)d_in[2];
    const float* sigma  = (const float*)d_in[3];
    const float* loraQ  = (const float*)d_in[4];
    float* out = (float*)d_out;

    bf16_t* Wb = (bf16_t*)d_ws;                                      // 32 MiB
    bf16_t* Xb = (bf16_t*)((char*)d_ws + (size_t)OUT_F * IN_F * 2);  // 128 MiB

    prep_kernel<<<CVT_BLOCKS + FOLD_BLOCKS, 256, 0, stream>>>(
        x, Xb, weight, loraP, sigma, loraQ, Wb);

    gemm256_kernel<<<(MTOT / 256) * (OUT_F / 256), 512, 0, stream>>>(Xb, Wb, out);
}